// Round 16
// baseline (2831.543 us; speedup 1.0000x reference)
//
#include <hip/hip_runtime.h>
#include <hip/hip_bf16.h>
#include <math.h>

#define D_F   64
#define IN_F  183     // 2*64 + 2*25 + 3 + 1 + 1
#define KS1   6       // layer-1 K tiles: 192 = 6*32; ks 0..3 = features (A1-precomputed), ks 4..5 = hist/tail
#define KS2   8       // layer-2/3 K tiles: 256 = 8*32
#define HID   256
#define HPITCH 264    // u16 per row: 528B; 528/16=33, 33%8==1 -> uniform bank spread
#define XP2   72      // u16 per x2 row: 144B = 9x16B, 9%8==1
#define BM    64      // pairs per block
#define BLK   256     // 4 waves; wave w owns hidden dims [64w,64w+64) x all 64 pairs

typedef unsigned short u16;
typedef __attribute__((ext_vector_type(8))) short bf16x8;
typedef __attribute__((ext_vector_type(4))) float f32x4;

__device__ __forceinline__ u16 f2bf(float v) {
    __hip_bfloat16 h = __float2bfloat16(v);   // RNE
    u16 u; __builtin_memcpy(&u, &h, 2); return u;
}

// ---------------------------------------------------------------------------
// Pack W (K x 256 f32, row-major) into MFMA fragment order (bf16):
//   Wp[((mt*KSs + ks)*64 + lane)*8 + j] = W[ks*32 + 8*(lane>>4) + j][mt*16 + (lane&15)]
// ---------------------------------------------------------------------------
__global__ void pack_w_kernel(const float* __restrict__ W, u16* __restrict__ Wp,
                              int K, int KSs)
{
    int g = blockIdx.x * 256 + threadIdx.x;
    int total = 16 * KSs * 64;
    if (g >= total) return;
    int lane = g & 63;
    int ks   = (g >> 6) % KSs;
    int mt   = (g >> 6) / KSs;
    int col  = mt * 16 + (lane & 15);
    int kb   = ks * 32 + 8 * (lane >> 4);
    u16 out[8];
    #pragma unroll
    for (int j = 0; j < 8; ++j) {
        int k = kb + j;
        out[j] = f2bf((k < K) ? W[(size_t)k * HID + col] : 0.0f);
    }
    *(bf16x8*)(Wp + (size_t)g * 8) = *(const bf16x8*)out;
}

// Pack W3 (256 x 3 f32): rows n<3 of W3^T, rest zero
__global__ void pack_w3_kernel(const float* __restrict__ W3, u16* __restrict__ W3p)
{
    int g = blockIdx.x * 256 + threadIdx.x;
    if (g >= KS2 * 64) return;
    int lane = g & 63;
    int ks   = g >> 6;
    int n    = lane & 15;
    int kb   = ks * 32 + 8 * (lane >> 4);
    u16 out[8];
    #pragma unroll
    for (int j = 0; j < 8; ++j)
        out[j] = f2bf((n < 3) ? W3[(size_t)(kb + j) * 3 + n] : 0.0f);
    *(bf16x8*)(W3p + (size_t)g * 8) = *(const bf16x8*)out;
}

// ---------------------------------------------------------------------------
// Per-node feature partials: A1[side][n][h] = sum_d features[n][d]*W1[side*64+d][h]
// f32-exact. Block = 16 nodes x 1 side; 256 threads (one per h).
// ---------------------------------------------------------------------------
__global__ __launch_bounds__(256)
void a1_kernel(const float* __restrict__ features, const float* __restrict__ W1,
               float* __restrict__ A1, int N)
{
    const int side = blockIdx.y;
    const int n0   = blockIdx.x * 16;
    const int h    = threadIdx.x;
    __shared__ float sf[16][D_F];
    for (int idx = threadIdx.x; idx < 16 * D_F; idx += 256) {
        int ni = idx >> 6, d = idx & 63;
        int n = n0 + ni;
        sf[ni][d] = (n < N) ? features[(size_t)n * D_F + d] : 0.0f;
    }
    __syncthreads();
    float acc[16];
    #pragma unroll
    for (int ni = 0; ni < 16; ++ni) acc[ni] = 0.0f;
    for (int d = 0; d < D_F; ++d) {
        float wv = W1[(size_t)(side * D_F + d) * HID + h];
        #pragma unroll
        for (int ni = 0; ni < 16; ++ni)
            acc[ni] = fmaf(sf[ni][d], wv, acc[ni]);
    }
    #pragma unroll
    for (int ni = 0; ni < 16; ++ni) {
        int n = n0 + ni;
        if (n < N) A1[((size_t)side * N + n) * HID + h] = acc[ni];
    }
}

// ---------------------------------------------------------------------------
// One-(t,k)-per-block fused MLP. Grid = (ceil(E/64), 1+3T); block y maps to
// (t,k): y=0 -> (0,0); y>=1 -> t=1+(y-1)/3, k=(y-1)%3. 256 threads / 4 fat
// waves: wave w owns hidden dims [64w,64w+64) x all 64 pairs.
// No state held across phases (acc1 dies at the h1 epilogue) -> peak VGPR
// ~110-120 on the proven 256-thr bare-__launch_bounds__ path; 44KB LDS ->
// up to 3 independent blocks/CU, which overlap each other's barrier drains
// (the resource every lockstep config lacked, rounds 3-15).
// One-hot is a column of x2 (c2==50+k -> 1.0) so layer-1 hist MFMA covers it.
// Single h-buffer (h1 then h2), 5 barriers per block.
// ---------------------------------------------------------------------------
__global__ __launch_bounds__(BLK)
void mfp_mlp_mfma(const float* __restrict__ states,
                  const float* __restrict__ distances,
                  const u16* __restrict__ W1p, const float* __restrict__ b1,
                  const u16* __restrict__ W2p, const float* __restrict__ b2,
                  const u16* __restrict__ W3p, const float* __restrict__ b3,
                  const float* __restrict__ A1,  // [2][N][256] f32 (in d_out tail)
                  const int* __restrict__ pairs_i, const int* __restrict__ pairs_j,
                  float* __restrict__ cond,
                  int N, int T1s, int E, int T)
{
    __shared__ u16   hbuf[BM * HPITCH];   // h1 then h2
    __shared__ u16   x2[BM * XP2];        // hist/tail/one-hot cols (orig k 128..191)
    __shared__ int   s_pi[BM], s_pj[BM], s_e[BM], s_val[BM];
    __shared__ float s_dist[BM];

    const int tid = threadIdx.x;
    const int y   = blockIdx.y;
    const int t   = (y == 0) ? 0 : (1 + (y - 1) / 3);
    const int k   = (y == 0) ? 0 : ((y - 1) % 3);

    // ---- per-pair meta ----
    if (tid < BM) {
        int pe = blockIdx.x * BM + tid;
        int valid = (pe < E) ? 1 : 0;
        int e = valid ? pe : 0;
        int pi = pairs_i[e], pj = pairs_j[e];
        s_e[tid] = e; s_val[tid] = valid; s_pi[tid] = pi; s_pj[tid] = pj;
        s_dist[tid] = distances[(long long)pi * N + pj];
    }
    __syncthreads();

    const int lane = tid & 63;
    const int w    = tid >> 6;     // wave id 0..3; hidden dims 64w..64w+63 (mt = 4w+mtl)
    const int lr   = lane & 15;
    const int lg   = lane >> 4;

    // ---- assemble x2 (orig cols 128..191): hist | one-hot(k) | dist | flag ----
    for (int idx = tid; idx < BM * 64; idx += BLK) {
        int m  = idx >> 6;
        int c2 = idx & 63;
        float v;
        if (c2 < 50) {
            int row = (c2 < 25) ? s_pi[m] : s_pj[m];
            int cc  = (c2 < 25) ? c2 : (c2 - 25);
            int l = cc / 5;
            int s = cc - l * 5;
            int tau = t - 4 + l;
            v = (tau >= 0) ? states[((size_t)row * T1s + tau) * 5 + s] : 0.0f;
        } else if (c2 < 53) {
            v = ((c2 - 50) == k) ? 1.0f : 0.0f;   // one-hot (block-constant k)
        } else if (c2 == 53) {
            v = s_dist[m];
        } else if (c2 == 54) {
            v = (t == 0) ? 1.0f : 0.0f;
        } else {
            v = 0.0f;
        }
        x2[m * XP2 + c2] = f2bf(v);
    }

    // ---- acc1 init: gather A1[pi] + A1[pj] (f32-exact feature part of L1) ----
    // Issued before the x2 barrier so L2 latency hides under it.
    // Sector-efficient: for one (mtl,nt), the 4 lg-lanes of a pair read 64B contiguous.
    f32x4 acc1[4][4];
    #pragma unroll
    for (int mtl = 0; mtl < 4; ++mtl) {
        int h0 = 16 * (4 * w + mtl) + 4 * lg;
        #pragma unroll
        for (int nt = 0; nt < 4; ++nt) {
            int m = 16 * nt + lr;
            f32x4 qa = *(const f32x4*)&A1[((size_t)s_pi[m]) * HID + h0];
            f32x4 qb = *(const f32x4*)&A1[((size_t)N + s_pj[m]) * HID + h0];
            acc1[mtl][nt] = qa + qb;
        }
    }
    __syncthreads();   // x2 ready

    // ---- layer-1 hist/tail/one-hot: 2 K-tiles (W1p ks = 4,5) ----
    #pragma unroll
    for (int ks2 = 0; ks2 < 2; ++ks2) {
        bf16x8 wfr[4];
        #pragma unroll
        for (int mtl = 0; mtl < 4; ++mtl)
            wfr[mtl] = *(const bf16x8*)(W1p + (((size_t)(4 * w + mtl) * KS1 + 4 + ks2) * 64 + lane) * 8);
        bf16x8 xfr[4];
        #pragma unroll
        for (int nt = 0; nt < 4; ++nt)
            xfr[nt] = *(const bf16x8*)(x2 + (16 * nt + lr) * XP2 + ks2 * 32 + 8 * lg);
        #pragma unroll
        for (int mtl = 0; mtl < 4; ++mtl)
            #pragma unroll
            for (int nt = 0; nt < 4; ++nt)
                acc1[mtl][nt] = __builtin_amdgcn_mfma_f32_16x16x32_bf16(wfr[mtl], xfr[nt], acc1[mtl][nt], 0, 0, 0);
    }

    // ---- h1 = relu(acc1 + b1) -> hbuf (acc1 dies here) ----
    #pragma unroll
    for (int mtl = 0; mtl < 4; ++mtl) {
        int h0 = 16 * (4 * w + mtl) + 4 * lg;
        f32x4 b1q = *(const f32x4*)&b1[h0];
        #pragma unroll
        for (int nt = 0; nt < 4; ++nt) {
            ushort4 p;
            p.x = f2bf(fmaxf(acc1[mtl][nt][0] + b1q[0], 0.0f));
            p.y = f2bf(fmaxf(acc1[mtl][nt][1] + b1q[1], 0.0f));
            p.z = f2bf(fmaxf(acc1[mtl][nt][2] + b1q[2], 0.0f));
            p.w = f2bf(fmaxf(acc1[mtl][nt][3] + b1q[3], 0.0f));
            *(ushort4*)(hbuf + (16 * nt + lr) * HPITCH + h0) = p;
        }
    }
    __syncthreads();   // h1 ready

    // ---- layer 2: acc2 = W2^T . h1^T ----
    f32x4 acc2[4][4];
    #pragma unroll
    for (int i = 0; i < 4; ++i)
        #pragma unroll
        for (int j = 0; j < 4; ++j)
            acc2[i][j] = (f32x4){0.f, 0.f, 0.f, 0.f};

    for (int ks = 0; ks < KS2; ++ks) {
        bf16x8 wfr[4];
        #pragma unroll
        for (int mtl = 0; mtl < 4; ++mtl)
            wfr[mtl] = *(const bf16x8*)(W2p + (((size_t)(4 * w + mtl) * KS2 + ks) * 64 + lane) * 8);
        bf16x8 hfr[4];
        #pragma unroll
        for (int nt = 0; nt < 4; ++nt)
            hfr[nt] = *(const bf16x8*)(hbuf + (16 * nt + lr) * HPITCH + ks * 32 + 8 * lg);
        #pragma unroll
        for (int mtl = 0; mtl < 4; ++mtl)
            #pragma unroll
            for (int nt = 0; nt < 4; ++nt)
                acc2[mtl][nt] = __builtin_amdgcn_mfma_f32_16x16x32_bf16(wfr[mtl], hfr[nt], acc2[mtl][nt], 0, 0, 0);
    }
    __syncthreads();   // all h1 reads done -> hbuf reusable

    // ---- h2 = relu(acc2 + b2) -> hbuf (overwrite) ----
    #pragma unroll
    for (int mtl = 0; mtl < 4; ++mtl) {
        int h0 = 16 * (4 * w + mtl) + 4 * lg;
        f32x4 b2q = *(const f32x4*)&b2[h0];
        #pragma unroll
        for (int nt = 0; nt < 4; ++nt) {
            ushort4 p;
            p.x = f2bf(fmaxf(acc2[mtl][nt][0] + b2q[0], 0.0f));
            p.y = f2bf(fmaxf(acc2[mtl][nt][1] + b2q[1], 0.0f));
            p.z = f2bf(fmaxf(acc2[mtl][nt][2] + b2q[2], 0.0f));
            p.w = f2bf(fmaxf(acc2[mtl][nt][3] + b2q[3], 0.0f));
            *(ushort4*)(hbuf + (16 * nt + lr) * HPITCH + h0) = p;
        }
    }
    __syncthreads();   // h2 ready

    // ---- layer 3: logits^T = W3^T . h2^T; wave w -> pairs 16w..16w+15 ----
    f32x4 acc3 = (f32x4){0.f, 0.f, 0.f, 0.f};
    for (int ks = 0; ks < KS2; ++ks) {
        bf16x8 hfr = *(const bf16x8*)(hbuf + (16 * w + lr) * HPITCH + ks * 32 + 8 * lg);
        bf16x8 wfr = *(const bf16x8*)(W3p + ((size_t)(ks * 64 + lane)) * 8);
        acc3 = __builtin_amdgcn_mfma_f32_16x16x32_bf16(wfr, hfr, acc3, 0, 0, 0);
    }
    // lane (lg==0, lr): acc3[r] = logit n=r of pair m = 16w+lr
    {
        int m = 16 * w + lr;
        if (lg == 0 && s_val[m]) {
            float l0 = acc3[0] + b3[0];
            float l1 = acc3[1] + b3[1];
            float l2 = acc3[2] + b3[2];
            float mx = fmaxf(l0, fmaxf(l1, l2));
            float e0 = expf(l0 - mx), e1 = expf(l1 - mx), e2 = expf(l2 - mx);
            float inv = 1.0f / (e0 + e1 + e2);
            float p0 = e0 * inv, p1 = e1 * inv, p2 = e2 * inv;
            size_t base = ((size_t)t * E + s_e[m]) * 9;
            if (t == 0) {
                #pragma unroll
                for (int kb = 0; kb < 3; ++kb) {
                    cond[base + kb * 3 + 0] = p0;
                    cond[base + kb * 3 + 1] = p1;
                    cond[base + kb * 3 + 2] = p2;
                }
            } else {
                cond[base + k * 3 + 0] = p0;
                cond[base + k * 3 + 1] = p1;
                cond[base + k * 3 + 2] = p2;
            }
        }
    }
}

// ---------------------------------------------------------------------------
// Marginal chain: m_t = m_{t-1} @ cond[t]
// ---------------------------------------------------------------------------
__global__ __launch_bounds__(256)
void mfp_marg_kernel(const float* __restrict__ cond,
                     float* __restrict__ marg,
                     int E, int T)
{
    int e = blockIdx.x * 256 + threadIdx.x;
    if (e >= E) return;
    const float* c0 = &cond[(size_t)e * 9];
    float m0 = c0[0], m1 = c0[1], m2 = c0[2];
    marg[(size_t)e * 3 + 0] = m0;
    marg[(size_t)e * 3 + 1] = m1;
    marg[(size_t)e * 3 + 2] = m2;
    for (int t = 1; t <= T; ++t) {
        const float* c9 = &cond[((size_t)t * E + e) * 9];
        float n0 = m0 * c9[0] + m1 * c9[3] + m2 * c9[6];
        float n1 = m0 * c9[1] + m1 * c9[4] + m2 * c9[7];
        float n2 = m0 * c9[2] + m1 * c9[5] + m2 * c9[8];
        m0 = n0; m1 = n1; m2 = n2;
        float* mo = &marg[((size_t)t * E + e) * 3];
        mo[0] = m0; mo[1] = m1; mo[2] = m2;
    }
}

// ---------------------------------------------------------------------------
extern "C" void kernel_launch(void* const* d_in, const int* in_sizes, int n_in,
                              void* d_out, int out_size, void* d_ws, size_t ws_size,
                              hipStream_t stream) {
    const float* features  = (const float*)d_in[0];
    const float* states    = (const float*)d_in[1];
    const float* distances = (const float*)d_in[2];
    const float* W1 = (const float*)d_in[3];
    const float* b1 = (const float*)d_in[4];
    const float* W2 = (const float*)d_in[5];
    const float* b2 = (const float*)d_in[6];
    const float* W3 = (const float*)d_in[7];
    const float* b3 = (const float*)d_in[8];
    const int* pairs_i = (const int*)d_in[9];
    const int* pairs_j = (const int*)d_in[10];

    const int N   = in_sizes[0] / D_F;             // 2000
    const int T1s = in_sizes[1] / (N * 5);         // 11
    const int E   = in_sizes[9];                   // 100000
    const int T   = out_size / (12 * E) - 1;       // 10

    float* cond = (float*)d_out;                            // (T+1, E, 3, 3)
    float* marg = (float*)d_out + (size_t)(T + 1) * E * 9;  // (T+1, E, 3)
    // A1 lives in the marg region (4.1MB of 13.2MB); the mlp kernel reads it
    // before the marg kernel overwrites the region -> replay-safe (recomputed
    // every launch).
    float* A1   = marg;

    u16* W1p = (u16*)d_ws;                                  // 16*KS1*64*8 elems
    u16* W2p = W1p + 16 * KS1 * 64 * 8;                     // 16*KS2*64*8 elems
    u16* W3p = W2p + 16 * KS2 * 64 * 8;                     // KS2*64*8 elems

    {
        int g1 = 16 * KS1 * 64;
        int g2 = 16 * KS2 * 64;
        int g3 = KS2 * 64;
        pack_w_kernel<<<(g1 + 255) / 256, 256, 0, stream>>>(W1, W1p, IN_F, KS1);
        pack_w_kernel<<<(g2 + 255) / 256, 256, 0, stream>>>(W2, W2p, HID, KS2);
        pack_w3_kernel<<<(g3 + 255) / 256, 256, 0, stream>>>(W3, W3p);
        dim3 ga((N + 15) / 16, 2);
        a1_kernel<<<ga, 256, 0, stream>>>(features, W1, A1, N);
    }

    dim3 grid((E + BM - 1) / BM, 1 + 3 * T);   // y -> (t,k) slice
    mfp_mlp_mfma<<<grid, BLK, 0, stream>>>(
        states, distances, W1p, b1, W2p, b2, W3p, b3, A1,
        pairs_i, pairs_j, cond, N, T1s, E, T);

    mfp_marg_kernel<<<(E + 255) / 256, 256, 0, stream>>>(cond, marg, E, T);
}

// Round 17
// 1077.376 us; speedup vs baseline: 2.6282x; 2.6282x over previous
//
#include <hip/hip_runtime.h>
#include <hip/hip_bf16.h>
#include <math.h>

#define D_F   64
#define IN_F  183     // 2*64 + 2*25 + 3 + 1 + 1
#define KS1   6       // layer-1 K tiles: 192 = 6*32; ks 0..3 = features (A1), ks 4..5 = hist/tail
#define KS2   8       // layer-2/3 K tiles: 256 = 8*32
#define HID   256
#define HPITCH 264    // u16 per row: 528B; 528/16=33, 33%8==1 -> uniform bank spread
#define XP2   72      // u16 per x2 row: 144B = 9x16B, 9%8==1
#define BM    64      // pairs per block
#define BLK   512     // 8 waves; wave w owns hidden dims [32w,32w+32) x all 64 pairs

typedef unsigned short u16;
typedef __attribute__((ext_vector_type(8))) short bf16x8;
typedef __attribute__((ext_vector_type(4))) float f32x4;

__device__ __forceinline__ u16 f2bf(float v) {
    __hip_bfloat16 h = __float2bfloat16(v);   // RNE
    u16 u; __builtin_memcpy(&u, &h, 2); return u;
}

// ---------------------------------------------------------------------------
// Pack W (K x 256 f32, row-major) into MFMA fragment order (bf16):
//   Wp[((mt*KSs + ks)*64 + lane)*8 + j] = W[ks*32 + 8*(lane>>4) + j][mt*16 + (lane&15)]
// ---------------------------------------------------------------------------
__global__ void pack_w_kernel(const float* __restrict__ W, u16* __restrict__ Wp,
                              int K, int KSs)
{
    int g = blockIdx.x * 256 + threadIdx.x;
    int total = 16 * KSs * 64;
    if (g >= total) return;
    int lane = g & 63;
    int ks   = (g >> 6) % KSs;
    int mt   = (g >> 6) / KSs;
    int col  = mt * 16 + (lane & 15);
    int kb   = ks * 32 + 8 * (lane >> 4);
    u16 out[8];
    #pragma unroll
    for (int j = 0; j < 8; ++j) {
        int k = kb + j;
        out[j] = f2bf((k < K) ? W[(size_t)k * HID + col] : 0.0f);
    }
    *(bf16x8*)(Wp + (size_t)g * 8) = *(const bf16x8*)out;
}

// Pack W3 (256 x 3 f32): rows n<3 of W3^T, rest zero
__global__ void pack_w3_kernel(const float* __restrict__ W3, u16* __restrict__ W3p)
{
    int g = blockIdx.x * 256 + threadIdx.x;
    if (g >= KS2 * 64) return;
    int lane = g & 63;
    int ks   = g >> 6;
    int n    = lane & 15;
    int kb   = ks * 32 + 8 * (lane >> 4);
    u16 out[8];
    #pragma unroll
    for (int j = 0; j < 8; ++j)
        out[j] = f2bf((n < 3) ? W3[(size_t)(kb + j) * 3 + n] : 0.0f);
    *(bf16x8*)(W3p + (size_t)g * 8) = *(const bf16x8*)out;
}

// ---------------------------------------------------------------------------
// Per-node feature partials: A1[side][n][h] = sum_d features[n][d]*W1[side*64+d][h]
// f32-exact. Block = 16 nodes x 1 side; 256 threads (one per h).
// ---------------------------------------------------------------------------
__global__ __launch_bounds__(256)
void a1_kernel(const float* __restrict__ features, const float* __restrict__ W1,
               float* __restrict__ A1, int N)
{
    const int side = blockIdx.y;
    const int n0   = blockIdx.x * 16;
    const int h    = threadIdx.x;
    __shared__ float sf[16][D_F];
    for (int idx = threadIdx.x; idx < 16 * D_F; idx += 256) {
        int ni = idx >> 6, d = idx & 63;
        int n = n0 + ni;
        sf[ni][d] = (n < N) ? features[(size_t)n * D_F + d] : 0.0f;
    }
    __syncthreads();
    float acc[16];
    #pragma unroll
    for (int ni = 0; ni < 16; ++ni) acc[ni] = 0.0f;
    for (int d = 0; d < D_F; ++d) {
        float wv = W1[(size_t)(side * D_F + d) * HID + h];
        #pragma unroll
        for (int ni = 0; ni < 16; ++ni)
            acc[ni] = fmaf(sf[ni][d], wv, acc[ni]);
    }
    #pragma unroll
    for (int ni = 0; ni < 16; ++ni) {
        int n = n0 + ni;
        if (n < N) A1[((size_t)side * N + n) * HID + h] = acc[ni];
    }
}

// ---------------------------------------------------------------------------
// Champion (round-11) schedule + A1 feature hoisting. Block = 64 pairs at ONE
// t (gridDim.y = T+1 -> 17K independent blocks, no intra-block t-loop).
// 512 threads / 8 waves; wave w owns hidden dims [32w,32w+32) x all 64 pairs.
// Per block: x2 assembly (hist/tail only, 64 cols), acc1 = A1[pi]+A1[pj]
// gathers (f32-exact, L2 latency hides under x2 assembly), 2 hist K-tiles
// (W1p ks=4,5), then the champion k-loop verbatim: pipelined h1(k+1) write,
// layer-2 MFMA, h2 -> hsB, layer-3 MFMA on waves 0..3, shuffle-free softmax,
// 2 barriers per k. One-hot handled via f32 ohq adds (L1 runs once).
// Live set ~116 VGPR (round-15 measured) <= 512-thr cap of 128 -> no spill.
// ---------------------------------------------------------------------------
__global__ __launch_bounds__(BLK)
void mfp_mlp_mfma(const float* __restrict__ states,
                  const float* __restrict__ distances,
                  const float* __restrict__ W1,   // f32, for one-hot rows 178..180
                  const u16* __restrict__ W1p, const float* __restrict__ b1,
                  const u16* __restrict__ W2p, const float* __restrict__ b2,
                  const u16* __restrict__ W3p, const float* __restrict__ b3,
                  const float* __restrict__ A1,  // [2][N][256] f32 (in d_out tail)
                  const int* __restrict__ pairs_i, const int* __restrict__ pairs_j,
                  float* __restrict__ cond,
                  int N, int T1s, int E, int T)
{
    extern __shared__ char smem[];
    u16* buf0 = (u16*)smem;              // [64][HPITCH]: h1 for odd k
    u16* buf1 = buf0 + BM * HPITCH;      // [64][HPITCH]: h1 for even k
    u16* hsB  = buf1 + BM * HPITCH;      // [64][HPITCH]: h2
    u16* x2   = hsB  + BM * HPITCH;      // [64][XP2]: hist/tail cols (orig 128..191)
    __shared__ int   s_pi[BM], s_pj[BM], s_e[BM], s_val[BM];
    __shared__ float s_dist[BM];

    const int tid = threadIdx.x;
    const int t   = blockIdx.y;
    const int nk  = (t == 0) ? 1 : 3;

    // ---- per-pair meta ----
    if (tid < BM) {
        int pe = blockIdx.x * BM + tid;
        int valid = (pe < E) ? 1 : 0;
        int e = valid ? pe : 0;
        int pi = pairs_i[e], pj = pairs_j[e];
        s_e[tid] = e; s_val[tid] = valid; s_pi[tid] = pi; s_pj[tid] = pj;
        s_dist[tid] = distances[(long long)pi * N + pj];
    }
    __syncthreads();

    const int lane = tid & 63;
    const int w    = tid >> 6;     // wave id 0..7; hidden dims 32w..32w+31 (mt = 2w+mtl)
    const int lr   = lane & 15;
    const int lg   = lane >> 4;

    // ---- assemble x2 (orig cols 128..191): hist | zeros(one-hot) | dist | flag ----
    for (int idx = tid; idx < BM * 64; idx += BLK) {
        int m  = idx >> 6;
        int c2 = idx & 63;
        float v;
        if (c2 < 50) {
            int row = (c2 < 25) ? s_pi[m] : s_pj[m];
            int cc  = (c2 < 25) ? c2 : (c2 - 25);
            int l = cc / 5;
            int s = cc - l * 5;
            int tau = t - 4 + l;
            v = (tau >= 0) ? states[((size_t)row * T1s + tau) * 5 + s] : 0.0f;
        } else if (c2 == 53) {
            v = s_dist[m];
        } else if (c2 == 54) {
            v = (t == 0) ? 1.0f : 0.0f;
        } else {
            v = 0.0f;   // one-hot cols zeroed (handled via ohq adds) + pad
        }
        x2[m * XP2 + c2] = f2bf(v);
    }

    // ---- acc1 init: gather A1[pi] + A1[pj] (f32-exact feature half of L1) ----
    // Issued before the x2 barrier so the L2 gather latency hides under it.
    f32x4 acc1[2][4];
    #pragma unroll
    for (int mtl = 0; mtl < 2; ++mtl) {
        int h0 = 16 * (2 * w + mtl) + 4 * lg;
        #pragma unroll
        for (int nt = 0; nt < 4; ++nt) {
            int m = 16 * nt + lr;
            f32x4 qa = *(const f32x4*)&A1[((size_t)s_pi[m]) * HID + h0];
            f32x4 qb = *(const f32x4*)&A1[((size_t)N + s_pj[m]) * HID + h0];
            acc1[mtl][nt] = qa + qb;
        }
    }

    // per-lane hidden-dim constants
    f32x4 b1q[2], b2q[2];
    #pragma unroll
    for (int mtl = 0; mtl < 2; ++mtl) {
        int h0 = 16 * (2 * w + mtl) + 4 * lg;
        b1q[mtl] = *(const f32x4*)&b1[h0];
        b2q[mtl] = *(const f32x4*)&b2[h0];
    }
    const float b30 = b3[0], b31 = b3[1], b32 = b3[2];

    __syncthreads();   // x2 ready

    // ---- layer-1 hist/tail part: 2 K-tiles (W1p ks = 4,5) ----
    #pragma unroll
    for (int ks2 = 0; ks2 < 2; ++ks2) {
        bf16x8 wfr[2];
        #pragma unroll
        for (int mtl = 0; mtl < 2; ++mtl)
            wfr[mtl] = *(const bf16x8*)(W1p + (((size_t)(2 * w + mtl) * KS1 + 4 + ks2) * 64 + lane) * 8);
        bf16x8 xfr[4];
        #pragma unroll
        for (int nt = 0; nt < 4; ++nt)
            xfr[nt] = *(const bf16x8*)(x2 + (16 * nt + lr) * XP2 + ks2 * 32 + 8 * lg);
        #pragma unroll
        for (int mtl = 0; mtl < 2; ++mtl)
            #pragma unroll
            for (int nt = 0; nt < 4; ++nt)
                acc1[mtl][nt] = __builtin_amdgcn_mfma_f32_16x16x32_bf16(wfr[mtl], xfr[nt], acc1[mtl][nt], 0, 0, 0);
    }

    // ---- prologue: h1(0) -> buf1 ----
    #pragma unroll
    for (int mtl = 0; mtl < 2; ++mtl) {
        int h0 = 16 * (2 * w + mtl) + 4 * lg;
        f32x4 ohq = *(const f32x4*)&W1[(size_t)178 * HID + h0];   // k = 0
        #pragma unroll
        for (int nt = 0; nt < 4; ++nt) {
            ushort4 p;
            p.x = f2bf(fmaxf(acc1[mtl][nt][0] + b1q[mtl][0] + ohq[0], 0.0f));
            p.y = f2bf(fmaxf(acc1[mtl][nt][1] + b1q[mtl][1] + ohq[1], 0.0f));
            p.z = f2bf(fmaxf(acc1[mtl][nt][2] + b1q[mtl][2] + ohq[2], 0.0f));
            p.w = f2bf(fmaxf(acc1[mtl][nt][3] + b1q[mtl][3] + ohq[3], 0.0f));
            *(ushort4*)(buf1 + (nt * 16 + lr) * HPITCH + h0) = p;
        }
    }
    __syncthreads();   // h1(0) ready

    // ---- k-loop (2 barriers per k) ----
    for (int k = 0; k < nk; ++k) {
        u16* cur = (k & 1) ? buf0 : buf1;   // h1(k)
        u16* nxt = (k & 1) ? buf1 : buf0;   // target for h1(k+1)

        // pipelined: write h1(k+1) -> nxt (depends only on acc1; ds_writes
        // drain while layer-2's global fragment loads + MFMAs run below)
        if (k + 1 < nk) {
            #pragma unroll
            for (int mtl = 0; mtl < 2; ++mtl) {
                int h0 = 16 * (2 * w + mtl) + 4 * lg;
                f32x4 ohq = *(const f32x4*)&W1[(size_t)(178 + k + 1) * HID + h0];
                #pragma unroll
                for (int nt = 0; nt < 4; ++nt) {
                    ushort4 p;
                    p.x = f2bf(fmaxf(acc1[mtl][nt][0] + b1q[mtl][0] + ohq[0], 0.0f));
                    p.y = f2bf(fmaxf(acc1[mtl][nt][1] + b1q[mtl][1] + ohq[1], 0.0f));
                    p.z = f2bf(fmaxf(acc1[mtl][nt][2] + b1q[mtl][2] + ohq[2], 0.0f));
                    p.w = f2bf(fmaxf(acc1[mtl][nt][3] + b1q[mtl][3] + ohq[3], 0.0f));
                    *(ushort4*)(nxt + (nt * 16 + lr) * HPITCH + h0) = p;
                }
            }
        }

        // layer 2: acc2 = W2^T . h1(k)^T
        f32x4 acc2[2][4];
        #pragma unroll
        for (int a = 0; a < 2; ++a)
            #pragma unroll
            for (int b = 0; b < 4; ++b)
                acc2[a][b] = (f32x4){0.f, 0.f, 0.f, 0.f};

        for (int ks = 0; ks < KS2; ++ks) {
            bf16x8 wfr[2];
            #pragma unroll
            for (int mtl = 0; mtl < 2; ++mtl)
                wfr[mtl] = *(const bf16x8*)(W2p + (((size_t)(2 * w + mtl) * KS2 + ks) * 64 + lane) * 8);
            bf16x8 hfr[4];
            #pragma unroll
            for (int nt = 0; nt < 4; ++nt)
                hfr[nt] = *(const bf16x8*)(cur + (nt * 16 + lr) * HPITCH + ks * 32 + 8 * lg);
            #pragma unroll
            for (int mtl = 0; mtl < 2; ++mtl)
                #pragma unroll
                for (int nt = 0; nt < 4; ++nt)
                    acc2[mtl][nt] = __builtin_amdgcn_mfma_f32_16x16x32_bf16(wfr[mtl], hfr[nt], acc2[mtl][nt], 0, 0, 0);
        }

        // h2 = relu(acc2 + b2) -> hsB
        #pragma unroll
        for (int mtl = 0; mtl < 2; ++mtl) {
            int h0 = 16 * (2 * w + mtl) + 4 * lg;
            #pragma unroll
            for (int nt = 0; nt < 4; ++nt) {
                ushort4 p;
                p.x = f2bf(fmaxf(acc2[mtl][nt][0] + b2q[mtl][0], 0.0f));
                p.y = f2bf(fmaxf(acc2[mtl][nt][1] + b2q[mtl][1], 0.0f));
                p.z = f2bf(fmaxf(acc2[mtl][nt][2] + b2q[mtl][2], 0.0f));
                p.w = f2bf(fmaxf(acc2[mtl][nt][3] + b2q[mtl][3], 0.0f));
                *(ushort4*)(hsB + (nt * 16 + lr) * HPITCH + h0) = p;
            }
        }
        __syncthreads();   // h2 ready; h1(k+1) ready

        // layer 3: logits^T = W3^T . h2^T, waves 0..3 -> pairs 16w..16w+15
        if (w < 4) {
            f32x4 acc3 = (f32x4){0.f, 0.f, 0.f, 0.f};
            for (int ks = 0; ks < KS2; ++ks) {
                bf16x8 hfr = *(const bf16x8*)(hsB + (w * 16 + lr) * HPITCH + ks * 32 + 8 * lg);
                bf16x8 wfr = *(const bf16x8*)(W3p + ((size_t)(ks * 64 + lane)) * 8);
                acc3 = __builtin_amdgcn_mfma_f32_16x16x32_bf16(wfr, hfr, acc3, 0, 0, 0);
            }
            int m = 16 * w + lr;
            if (lg == 0 && s_val[m]) {
                float l0 = acc3[0] + b30;
                float l1 = acc3[1] + b31;
                float l2 = acc3[2] + b32;
                float mx = fmaxf(l0, fmaxf(l1, l2));
                float e0 = expf(l0 - mx), e1 = expf(l1 - mx), e2 = expf(l2 - mx);
                float inv = 1.0f / (e0 + e1 + e2);
                float p0 = e0 * inv, p1 = e1 * inv, p2 = e2 * inv;
                size_t base = ((size_t)t * E + s_e[m]) * 9;
                if (t == 0) {
                    #pragma unroll
                    for (int kb = 0; kb < 3; ++kb) {
                        cond[base + kb * 3 + 0] = p0;
                        cond[base + kb * 3 + 1] = p1;
                        cond[base + kb * 3 + 2] = p2;
                    }
                } else {
                    cond[base + k * 3 + 0] = p0;
                    cond[base + k * 3 + 1] = p1;
                    cond[base + k * 3 + 2] = p2;
                }
            }
        }
        __syncthreads();   // hsB reads done; next k may overwrite buffers
    }
}

// ---------------------------------------------------------------------------
// Marginal chain: m_t = m_{t-1} @ cond[t]
// ---------------------------------------------------------------------------
__global__ __launch_bounds__(256)
void mfp_marg_kernel(const float* __restrict__ cond,
                     float* __restrict__ marg,
                     int E, int T)
{
    int e = blockIdx.x * 256 + threadIdx.x;
    if (e >= E) return;
    const float* c0 = &cond[(size_t)e * 9];
    float m0 = c0[0], m1 = c0[1], m2 = c0[2];
    marg[(size_t)e * 3 + 0] = m0;
    marg[(size_t)e * 3 + 1] = m1;
    marg[(size_t)e * 3 + 2] = m2;
    for (int t = 1; t <= T; ++t) {
        const float* c9 = &cond[((size_t)t * E + e) * 9];
        float n0 = m0 * c9[0] + m1 * c9[3] + m2 * c9[6];
        float n1 = m0 * c9[1] + m1 * c9[4] + m2 * c9[7];
        float n2 = m0 * c9[2] + m1 * c9[5] + m2 * c9[8];
        m0 = n0; m1 = n1; m2 = n2;
        float* mo = &marg[((size_t)t * E + e) * 3];
        mo[0] = m0; mo[1] = m1; mo[2] = m2;
    }
}

// ---------------------------------------------------------------------------
extern "C" void kernel_launch(void* const* d_in, const int* in_sizes, int n_in,
                              void* d_out, int out_size, void* d_ws, size_t ws_size,
                              hipStream_t stream) {
    const float* features  = (const float*)d_in[0];
    const float* states    = (const float*)d_in[1];
    const float* distances = (const float*)d_in[2];
    const float* W1 = (const float*)d_in[3];
    const float* b1 = (const float*)d_in[4];
    const float* W2 = (const float*)d_in[5];
    const float* b2 = (const float*)d_in[6];
    const float* W3 = (const float*)d_in[7];
    const float* b3 = (const float*)d_in[8];
    const int* pairs_i = (const int*)d_in[9];
    const int* pairs_j = (const int*)d_in[10];

    const int N   = in_sizes[0] / D_F;             // 2000
    const int T1s = in_sizes[1] / (N * 5);         // 11
    const int E   = in_sizes[9];                   // 100000
    const int T   = out_size / (12 * E) - 1;       // 10

    float* cond = (float*)d_out;                            // (T+1, E, 3, 3)
    float* marg = (float*)d_out + (size_t)(T + 1) * E * 9;  // (T+1, E, 3)
    // A1 lives in the marg region (4.1MB of 13.2MB); the mlp kernel reads it
    // before the marg kernel overwrites the region. Recomputed every launch
    // -> deterministic, graph-capture-safe.
    float* A1   = marg;

    u16* W1p = (u16*)d_ws;                                  // 16*KS1*64*8 elems
    u16* W2p = W1p + 16 * KS1 * 64 * 8;                     // 16*KS2*64*8 elems
    u16* W3p = W2p + 16 * KS2 * 64 * 8;                     // KS2*64*8 elems

    {
        int g1 = 16 * KS1 * 64;
        int g2 = 16 * KS2 * 64;
        int g3 = KS2 * 64;
        pack_w_kernel<<<(g1 + 255) / 256, 256, 0, stream>>>(W1, W1p, IN_F, KS1);
        pack_w_kernel<<<(g2 + 255) / 256, 256, 0, stream>>>(W2, W2p, HID, KS2);
        pack_w3_kernel<<<(g3 + 255) / 256, 256, 0, stream>>>(W3, W3p);
        dim3 ga((N + 15) / 16, 2);
        a1_kernel<<<ga, 256, 0, stream>>>(features, W1, A1, N);
    }

    dim3 grid((E + BM - 1) / BM, T + 1);
    const size_t lds_bytes = (size_t)3 * BM * HPITCH * sizeof(u16)
                           + (size_t)BM * XP2 * sizeof(u16);   // 110592 B

    mfp_mlp_mfma<<<grid, BLK, lds_bytes, stream>>>(
        states, distances, W1, W1p, b1, W2p, b2, W3p, b3, A1,
        pairs_i, pairs_j, cond, N, T1s, E, T);

    mfp_marg_kernel<<<(E + 255) / 256, 256, 0, stream>>>(cond, marg, E, T);
}

// Round 18
// 862.232 us; speedup vs baseline: 3.2840x; 1.2495x over previous
//
#include <hip/hip_runtime.h>
#include <hip/hip_bf16.h>
#include <math.h>

#define D_F   64
#define IN_F  183     // 2*64 + 2*25 + 3 + 1 + 1
#define KS1   6       // layer-1 K tiles: 192 = 6*32 (padded from 183)
#define KS2   8       // layer-2/3 K tiles: 256 = 8*32
#define HID   256
#define HPITCH 264    // u16 per row: 528B; 528/16=33, 33%8==1 -> uniform bank spread
#define BM    64      // pairs per block
#define BLK   512     // 8 waves; wave w owns hidden tiles {2w,2w+1} x all 64 pairs

typedef unsigned short u16;
typedef __attribute__((ext_vector_type(8))) short bf16x8;
typedef __attribute__((ext_vector_type(4))) float f32x4;

__device__ __forceinline__ u16 f2bf(float v) {
    __hip_bfloat16 h = __float2bfloat16(v);   // RNE
    u16 u; __builtin_memcpy(&u, &h, 2); return u;
}

// ---------------------------------------------------------------------------
// Pack W (K x 256 f32, row-major) into MFMA fragment order (bf16):
//   Wp[((mt*KSs + ks)*64 + lane)*8 + j] = W[ks*32 + 8*(lane>>4) + j][mt*16 + (lane&15)]
// Serves as the A-operand (W^T rows) in the transposed scheme.
// ---------------------------------------------------------------------------
__global__ void pack_w_kernel(const float* __restrict__ W, u16* __restrict__ Wp,
                              int K, int KSs)
{
    int g = blockIdx.x * 256 + threadIdx.x;
    int total = 16 * KSs * 64;
    if (g >= total) return;
    int lane = g & 63;
    int ks   = (g >> 6) % KSs;
    int mt   = (g >> 6) / KSs;
    int col  = mt * 16 + (lane & 15);
    int kb   = ks * 32 + 8 * (lane >> 4);
    u16 out[8];
    #pragma unroll
    for (int j = 0; j < 8; ++j) {
        int k = kb + j;
        out[j] = f2bf((k < K) ? W[(size_t)k * HID + col] : 0.0f);
    }
    *(bf16x8*)(Wp + (size_t)g * 8) = *(const bf16x8*)out;
}

// Pack W3 (256 x 3 f32): rows n<3 of W3^T, rest zero
__global__ void pack_w3_kernel(const float* __restrict__ W3, u16* __restrict__ W3p)
{
    int g = blockIdx.x * 256 + threadIdx.x;
    if (g >= KS2 * 64) return;
    int lane = g & 63;
    int ks   = g >> 6;
    int n    = lane & 15;
    int kb   = ks * 32 + 8 * (lane >> 4);
    u16 out[8];
    #pragma unroll
    for (int j = 0; j < 8; ++j)
        out[j] = f2bf((n < 3) ? W3[(size_t)(kb + j) * 3 + n] : 0.0f);
    *(bf16x8*)(W3p + (size_t)g * 8) = *(const bf16x8*)out;
}

// ---------------------------------------------------------------------------
// Champion (round-11) transposed pair-block fused MLP + all-wave layer-3.
// Block = 64 pairs at one t (gridDim.y=T+1), 8 waves; wave w owns hidden
// tiles {2w,2w+1} (dims 32w..32w+31) x all 64 pairs: acc[2 mtl][4 nt].
// h1(k+1) is written at the TOP of iteration k (independent given acc1) so
// its VALU/ds_write latency hides under layer-2's loads+MFMAs. Triple LDS
// buffer: buf0 = x then h1(odd k); buf1 = h1(even k); hsB = h2. 2 barriers/k.
// Layer 3 split across ALL 8 waves: wave (a=w&3, half=w>>2) computes the
// K-half [128*half,128*half+128) for pairs 16a..16a+15 (4 chained MFMAs,
// was 8 on half the waves); upper waves stash partial logits in s_l3; the
// existing end-of-k barrier publishes; lower waves sum + softmax.
// Bare __launch_bounds__(512): proven 108 VGPR, no spill (rounds 4/9/10/12:
// every min-waves hint or >=1024-thr path caps VGPR and spills to scratch).
// ---------------------------------------------------------------------------
__global__ __launch_bounds__(BLK)
void mfp_mlp_mfma(const float* __restrict__ features,
                  const float* __restrict__ states,
                  const float* __restrict__ distances,
                  const float* __restrict__ W1,   // f32, for one-hot rows 178..180
                  const u16* __restrict__ W1p, const float* __restrict__ b1,
                  const u16* __restrict__ W2p, const float* __restrict__ b2,
                  const u16* __restrict__ W3p, const float* __restrict__ b3,
                  const int* __restrict__ pairs_i, const int* __restrict__ pairs_j,
                  float* __restrict__ cond,
                  int N, int T1s, int E, int T)
{
    extern __shared__ char smem[];
    u16* buf0 = (u16*)smem;              // [64][HPITCH]: x, then h1 for odd k
    u16* buf1 = buf0 + BM * HPITCH;      // [64][HPITCH]: h1 for even k
    u16* hsB  = buf1 + BM * HPITCH;      // [64][HPITCH]: h2
    __shared__ int   s_pi[BM], s_pj[BM], s_e[BM], s_val[BM];
    __shared__ float s_dist[BM];
    __shared__ float s_l3[4][16][3];     // upper-wave partial logits

    const int tid = threadIdx.x;
    const int t   = blockIdx.y;
    const int nk  = (t == 0) ? 1 : 3;

    // ---- per-pair meta ----
    if (tid < BM) {
        int pe = blockIdx.x * BM + tid;
        int valid = (pe < E) ? 1 : 0;
        int e = valid ? pe : 0;
        int pi = pairs_i[e], pj = pairs_j[e];
        s_e[tid] = e; s_val[tid] = valid; s_pi[tid] = pi; s_pj[tid] = pj;
        s_dist[tid] = distances[(long long)pi * N + pj];
    }
    __syncthreads();

    // ---- assemble x rows (bf16) into buf0, one-hot cols (178..180) zeroed ----
    u16* xs = buf0;
    for (int idx = tid; idx < BM * 32; idx += BLK) {     // cols 0..127: features
        int m = idx >> 5;
        int q = idx & 31;
        int src = (q < 16) ? s_pi[m] : s_pj[m];
        int c4  = (q & 15) * 4;
        float4 f = *(const float4*)&features[(size_t)src * D_F + c4];
        int c = ((q < 16) ? 0 : 64) + c4;
        ushort4 o;
        o.x = f2bf(f.x); o.y = f2bf(f.y); o.z = f2bf(f.z); o.w = f2bf(f.w);
        *(ushort4*)(xs + m * HPITCH + c) = o;
    }
    for (int idx = tid; idx < BM * 64; idx += BLK) {     // cols 128..191
        int m = idx >> 6;
        int c = 128 + (idx & 63);
        float v;
        if (c < 178) {
            int cc = c - 128;
            int row = (cc < 25) ? s_pi[m] : s_pj[m];
            int c2  = (cc < 25) ? cc : (cc - 25);
            int l = c2 / 5;
            int s = c2 - l * 5;
            int tau = t - 4 + l;
            v = (tau >= 0) ? states[((size_t)row * T1s + tau) * 5 + s] : 0.0f;
        } else if (c == 181) {
            v = s_dist[m];
        } else if (c == 182) {
            v = (t == 0) ? 1.0f : 0.0f;
        } else {
            v = 0.0f;   // one-hot 178..180 and pad 183..191
        }
        xs[m * HPITCH + c] = f2bf(v);
    }
    __syncthreads();

    const int lane = tid & 63;
    const int w    = tid >> 6;     // wave id 0..7
    const int lr   = lane & 15;
    const int lg   = lane >> 4;
    // wave w owns hidden tiles mt = 2w, 2w+1 (hidden dims 32w .. 32w+31)

    // ---- layer 1 (once): acc1 = W1^T . x^T, held across the k-loop ----
    // lane: pair m = 16*nt + lr ; hidden h = 16*(2w+mtl) + 4*lg + r
    f32x4 acc1[2][4];
    #pragma unroll
    for (int a = 0; a < 2; ++a)
        #pragma unroll
        for (int b = 0; b < 4; ++b)
            acc1[a][b] = (f32x4){0.f, 0.f, 0.f, 0.f};

    for (int ks = 0; ks < KS1; ++ks) {
        bf16x8 wfr[2];
        #pragma unroll
        for (int mtl = 0; mtl < 2; ++mtl)
            wfr[mtl] = *(const bf16x8*)(W1p + (((size_t)(2 * w + mtl) * KS1 + ks) * 64 + lane) * 8);
        bf16x8 xfr[4];
        #pragma unroll
        for (int nt = 0; nt < 4; ++nt)
            xfr[nt] = *(const bf16x8*)(xs + (nt * 16 + lr) * HPITCH + ks * 32 + 8 * lg);
        #pragma unroll
        for (int mtl = 0; mtl < 2; ++mtl)
            #pragma unroll
            for (int nt = 0; nt < 4; ++nt)
                acc1[mtl][nt] = __builtin_amdgcn_mfma_f32_16x16x32_bf16(wfr[mtl], xfr[nt], acc1[mtl][nt], 0, 0, 0);
    }

    // per-lane hidden-dim constants: h = 16*(2w+mtl) + 4*lg + r, r=0..3
    f32x4 b1q[2], b2q[2];
    #pragma unroll
    for (int mtl = 0; mtl < 2; ++mtl) {
        int h0 = 16 * (2 * w + mtl) + 4 * lg;
        b1q[mtl] = *(const f32x4*)&b1[h0];
        b2q[mtl] = *(const f32x4*)&b2[h0];
    }
    const float b30 = b3[0], b31 = b3[1], b32 = b3[2];

    __syncthreads();   // all x reads done (L1 complete everywhere)

    // ---- prologue: h1(0) -> buf1 ----
    #pragma unroll
    for (int mtl = 0; mtl < 2; ++mtl) {
        int h0 = 16 * (2 * w + mtl) + 4 * lg;
        f32x4 ohq = *(const f32x4*)&W1[(size_t)178 * HID + h0];   // k = 0
        #pragma unroll
        for (int nt = 0; nt < 4; ++nt) {
            ushort4 p;
            p.x = f2bf(fmaxf(acc1[mtl][nt][0] + b1q[mtl][0] + ohq[0], 0.0f));
            p.y = f2bf(fmaxf(acc1[mtl][nt][1] + b1q[mtl][1] + ohq[1], 0.0f));
            p.z = f2bf(fmaxf(acc1[mtl][nt][2] + b1q[mtl][2] + ohq[2], 0.0f));
            p.w = f2bf(fmaxf(acc1[mtl][nt][3] + b1q[mtl][3] + ohq[3], 0.0f));
            *(ushort4*)(buf1 + (nt * 16 + lr) * HPITCH + h0) = p;
        }
    }
    __syncthreads();   // h1(0) ready

    // ---- k-loop (2 barriers per k) ----
    for (int k = 0; k < nk; ++k) {
        u16* cur = (k & 1) ? buf0 : buf1;   // h1(k)
        u16* nxt = (k & 1) ? buf1 : buf0;   // target for h1(k+1)

        // pipelined: write h1(k+1) -> nxt (depends only on acc1; ds_writes
        // drain while layer-2's global fragment loads + MFMAs run below)
        if (k + 1 < nk) {
            #pragma unroll
            for (int mtl = 0; mtl < 2; ++mtl) {
                int h0 = 16 * (2 * w + mtl) + 4 * lg;
                f32x4 ohq = *(const f32x4*)&W1[(size_t)(178 + k + 1) * HID + h0];
                #pragma unroll
                for (int nt = 0; nt < 4; ++nt) {
                    ushort4 p;
                    p.x = f2bf(fmaxf(acc1[mtl][nt][0] + b1q[mtl][0] + ohq[0], 0.0f));
                    p.y = f2bf(fmaxf(acc1[mtl][nt][1] + b1q[mtl][1] + ohq[1], 0.0f));
                    p.z = f2bf(fmaxf(acc1[mtl][nt][2] + b1q[mtl][2] + ohq[2], 0.0f));
                    p.w = f2bf(fmaxf(acc1[mtl][nt][3] + b1q[mtl][3] + ohq[3], 0.0f));
                    *(ushort4*)(nxt + (nt * 16 + lr) * HPITCH + h0) = p;
                }
            }
        }

        // layer 2: acc2 = W2^T . h1(k)^T
        f32x4 acc2[2][4];
        #pragma unroll
        for (int a = 0; a < 2; ++a)
            #pragma unroll
            for (int b = 0; b < 4; ++b)
                acc2[a][b] = (f32x4){0.f, 0.f, 0.f, 0.f};

        for (int ks = 0; ks < KS2; ++ks) {
            bf16x8 wfr[2];
            #pragma unroll
            for (int mtl = 0; mtl < 2; ++mtl)
                wfr[mtl] = *(const bf16x8*)(W2p + (((size_t)(2 * w + mtl) * KS2 + ks) * 64 + lane) * 8);
            bf16x8 hfr[4];
            #pragma unroll
            for (int nt = 0; nt < 4; ++nt)
                hfr[nt] = *(const bf16x8*)(cur + (nt * 16 + lr) * HPITCH + ks * 32 + 8 * lg);
            #pragma unroll
            for (int mtl = 0; mtl < 2; ++mtl)
                #pragma unroll
                for (int nt = 0; nt < 4; ++nt)
                    acc2[mtl][nt] = __builtin_amdgcn_mfma_f32_16x16x32_bf16(wfr[mtl], hfr[nt], acc2[mtl][nt], 0, 0, 0);
        }

        // h2 = relu(acc2 + b2) -> hsB (own buffer; prev L3's hsB reads
        // finished at the post-L3 barrier)
        #pragma unroll
        for (int mtl = 0; mtl < 2; ++mtl) {
            int h0 = 16 * (2 * w + mtl) + 4 * lg;
            #pragma unroll
            for (int nt = 0; nt < 4; ++nt) {
                ushort4 p;
                p.x = f2bf(fmaxf(acc2[mtl][nt][0] + b2q[mtl][0], 0.0f));
                p.y = f2bf(fmaxf(acc2[mtl][nt][1] + b2q[mtl][1], 0.0f));
                p.z = f2bf(fmaxf(acc2[mtl][nt][2] + b2q[mtl][2], 0.0f));
                p.w = f2bf(fmaxf(acc2[mtl][nt][3] + b2q[mtl][3], 0.0f));
                *(ushort4*)(hsB + (nt * 16 + lr) * HPITCH + h0) = p;
            }
        }
        __syncthreads();   // h2 ready; h1(k+1) ready

        // layer 3 split across ALL waves: wave (a3=w&3, half=w>>2) computes
        // K-half [128*half, 128*half+128) of logits^T for pairs 16a3..16a3+15.
        const int a3 = w & 3;
        f32x4 acc3 = (f32x4){0.f, 0.f, 0.f, 0.f};
        {
            const int ks0 = (w >> 2) * 4;
            #pragma unroll
            for (int kss = 0; kss < 4; ++kss) {
                int ks = ks0 + kss;
                bf16x8 hfr = *(const bf16x8*)(hsB + (a3 * 16 + lr) * HPITCH + ks * 32 + 8 * lg);
                bf16x8 wfr = *(const bf16x8*)(W3p + ((size_t)(ks * 64 + lane)) * 8);
                acc3 = __builtin_amdgcn_mfma_f32_16x16x32_bf16(wfr, hfr, acc3, 0, 0, 0);
            }
            if (w >= 4 && lg == 0) {   // stash upper-half partial logits
                s_l3[a3][lr][0] = acc3[0];
                s_l3[a3][lr][1] = acc3[1];
                s_l3[a3][lr][2] = acc3[2];
            }
        }
        __syncthreads();   // publishes s_l3; hsB reads done; buffers reusable

        // lower waves: combine halves + softmax + store
        // (safe vs next k: upper waves' next stash happens only after the
        //  next "h2 ready" barrier, which all waves must reach first)
        if (w < 4) {
            int m = 16 * a3 + lr;
            if (lg == 0 && s_val[m]) {
                float l0 = acc3[0] + s_l3[a3][lr][0] + b30;
                float l1 = acc3[1] + s_l3[a3][lr][1] + b31;
                float l2 = acc3[2] + s_l3[a3][lr][2] + b32;
                float mx = fmaxf(l0, fmaxf(l1, l2));
                float e0 = expf(l0 - mx), e1 = expf(l1 - mx), e2 = expf(l2 - mx);
                float inv = 1.0f / (e0 + e1 + e2);
                float p0 = e0 * inv, p1 = e1 * inv, p2 = e2 * inv;
                size_t base = ((size_t)t * E + s_e[m]) * 9;
                if (t == 0) {
                    #pragma unroll
                    for (int kb = 0; kb < 3; ++kb) {
                        cond[base + kb * 3 + 0] = p0;
                        cond[base + kb * 3 + 1] = p1;
                        cond[base + kb * 3 + 2] = p2;
                    }
                } else {
                    cond[base + k * 3 + 0] = p0;
                    cond[base + k * 3 + 1] = p1;
                    cond[base + k * 3 + 2] = p2;
                }
            }
        }
    }
}

// ---------------------------------------------------------------------------
// Marginal chain: m_t = m_{t-1} @ cond[t]
// ---------------------------------------------------------------------------
__global__ __launch_bounds__(256)
void mfp_marg_kernel(const float* __restrict__ cond,
                     float* __restrict__ marg,
                     int E, int T)
{
    int e = blockIdx.x * 256 + threadIdx.x;
    if (e >= E) return;
    const float* c0 = &cond[(size_t)e * 9];
    float m0 = c0[0], m1 = c0[1], m2 = c0[2];
    marg[(size_t)e * 3 + 0] = m0;
    marg[(size_t)e * 3 + 1] = m1;
    marg[(size_t)e * 3 + 2] = m2;
    for (int t = 1; t <= T; ++t) {
        const float* c9 = &cond[((size_t)t * E + e) * 9];
        float n0 = m0 * c9[0] + m1 * c9[3] + m2 * c9[6];
        float n1 = m0 * c9[1] + m1 * c9[4] + m2 * c9[7];
        float n2 = m0 * c9[2] + m1 * c9[5] + m2 * c9[8];
        m0 = n0; m1 = n1; m2 = n2;
        float* mo = &marg[((size_t)t * E + e) * 3];
        mo[0] = m0; mo[1] = m1; mo[2] = m2;
    }
}

// ---------------------------------------------------------------------------
extern "C" void kernel_launch(void* const* d_in, const int* in_sizes, int n_in,
                              void* d_out, int out_size, void* d_ws, size_t ws_size,
                              hipStream_t stream) {
    const float* features  = (const float*)d_in[0];
    const float* states    = (const float*)d_in[1];
    const float* distances = (const float*)d_in[2];
    const float* W1 = (const float*)d_in[3];
    const float* b1 = (const float*)d_in[4];
    const float* W2 = (const float*)d_in[5];
    const float* b2 = (const float*)d_in[6];
    const float* W3 = (const float*)d_in[7];
    const float* b3 = (const float*)d_in[8];
    const int* pairs_i = (const int*)d_in[9];
    const int* pairs_j = (const int*)d_in[10];

    const int N   = in_sizes[0] / D_F;             // 2000
    const int T1s = in_sizes[1] / (N * 5);         // 11
    const int E   = in_sizes[9];                   // 100000
    const int T   = out_size / (12 * E) - 1;       // 10

    float* cond = (float*)d_out;                            // (T+1, E, 3, 3)
    float* marg = (float*)d_out + (size_t)(T + 1) * E * 9;  // (T+1, E, 3)

    u16* W1p = (u16*)d_ws;                                  // 16*KS1*64*8 elems
    u16* W2p = W1p + 16 * KS1 * 64 * 8;                     // 16*KS2*64*8 elems
    u16* W3p = W2p + 16 * KS2 * 64 * 8;                     // KS2*64*8 elems

    {
        int g1 = 16 * KS1 * 64;
        int g2 = 16 * KS2 * 64;
        int g3 = KS2 * 64;
        pack_w_kernel<<<(g1 + 255) / 256, 256, 0, stream>>>(W1, W1p, IN_F, KS1);
        pack_w_kernel<<<(g2 + 255) / 256, 256, 0, stream>>>(W2, W2p, HID, KS2);
        pack_w3_kernel<<<(g3 + 255) / 256, 256, 0, stream>>>(W3, W3p);
    }

    dim3 grid((E + BM - 1) / BM, T + 1);
    const size_t lds_bytes = (size_t)3 * BM * HPITCH * sizeof(u16);   // 101376 B

    mfp_mlp_mfma<<<grid, BLK, lds_bytes, stream>>>(
        features, states, distances, W1, W1p, b1, W2p, b2, W3p, b3,
        pairs_i, pairs_j, cond, N, T1s, E, T);

    mfp_marg_kernel<<<(E + 255) / 256, 256, 0, stream>>>(cond, marg, E, T);
}